// Round 7
// baseline (2897.508 us; speedup 1.0000x reference)
//
#include <hip/hip_runtime.h>

#define TT  64
#define BSZ 512
#define ISZ 512
#define HSZ 1024

typedef short bf16x8 __attribute__((ext_vector_type(8)));
typedef float f32x4 __attribute__((ext_vector_type(4)));
typedef unsigned short u16x8 __attribute__((ext_vector_type(8)));

typedef const __attribute__((address_space(1))) unsigned int* gas_t;
typedef __attribute__((address_space(3))) unsigned int* las_t;

__device__ __forceinline__ unsigned short f2bf(float f) {
    unsigned int u = __float_as_uint(f);
    unsigned int r = u + 0x7FFFu + ((u >> 16) & 1u);   // RNE
    return (unsigned short)(r >> 16);
}

__global__ void cast_f32_to_bf16(const float* __restrict__ in,
                                 unsigned short* __restrict__ out, int n8) {
    int i = blockIdx.x * blockDim.x + threadIdx.x;
    if (i >= n8) return;
    const float4* p = (const float4*)(in + (size_t)i * 8);
    float4 v0 = p[0], v1 = p[1];
    u16x8 o;
    o[0] = f2bf(v0.x); o[1] = f2bf(v0.y); o[2] = f2bf(v0.z); o[3] = f2bf(v0.w);
    o[4] = f2bf(v1.x); o[5] = f2bf(v1.y); o[6] = f2bf(v1.z); o[7] = f2bf(v1.w);
    *(u16x8*)(out + (size_t)i * 8) = o;
}

__global__ void bias_combine(const float* __restrict__ a,
                             const float* __restrict__ b,
                             float* __restrict__ o) {
    int i = blockIdx.x * blockDim.x + threadIdx.x;
    if (i < 4 * HSZ) o[i] = a[i] + b[i];
}

__global__ void zero_arr(int* p, int n) {
    int i = blockIdx.x * blockDim.x + threadIdx.x;
    if (i < n) p[i] = 0;
}

// Persistent LSTM: 256 blocks (1/CU via 144KB LDS), 1024 threads = 16 waves
// = 4 waves/SIMD. Waves: q = wv&3 (32 b-rows), kh = wv>>2 (K quarter).
// Block (mi=bid>>6, ni=bid&63): b-rows [mi*128,+128), h-cols [ni*16,+16).
// W_hh slice LDS-resident (128K, XOR-swizzled). W_ih/x/h read direct from
// global (software-pipelined). K-quarters merged via 16KB LDS reduce.
// Cross-step sync: 4 independent 64-block barriers, RELAXED polls +
// single acquire fence (avoids per-poll L2 invalidation).
__global__ __launch_bounds__(1024, 4) void lstm_persist(
    const unsigned short* __restrict__ xb,    // [TT, BSZ, ISZ] bf16
    const unsigned short* __restrict__ Wihb,  // [4096, 512]
    const unsigned short* __restrict__ Whhb,  // [4096, 1024]
    const float* __restrict__ bias,           // [4096]
    float* __restrict__ out,                  // fp32 output
    unsigned short* __restrict__ hb0,
    unsigned short* __restrict__ hb1,
    int* __restrict__ arrive)
{
    __shared__ unsigned short WhL[64 * 1024];   // 128 KiB persistent W_hh
    __shared__ float WS[4096];                  //  16 KiB k-reduce

    const int tid  = threadIdx.x;
    const int lane = tid & 63;
    const int wv   = tid >> 6;       // 0..15
    const int q    = wv & 3;         // b-group (32 rows)
    const int kh   = wv >> 2;        // K quarter (0..3)
    const int lr   = lane & 15;
    const int kq   = lane >> 4;      // 0..3
    const int mi   = blockIdx.x >> 6;
    const int ni   = blockIdx.x & 63;
    const int b0   = mi * 128;
    const int hc0  = ni * 16;

    // ---- issue persistent W_hh stage (async; overlaps x_part(0) below) ----
    // LDS[row r][slot u] = G[row r][slot u ^ (r&7)]  (read undoes the XOR)
    #pragma unroll
    for (int i = 0; i < 8; ++i) {
        const int li = wv * 8 + i;            // 1KB unit, 0..127
        const int r = li >> 1, half = li & 1;
        const int grow = (r >> 4) * HSZ + hc0 + (r & 15);
        const int gslot = (half * 64 + lane) ^ (r & 7);
        const unsigned short* g = Whhb + (size_t)grow * HSZ + (size_t)gslot * 8;
        __builtin_amdgcn_global_load_lds((gas_t)g, (las_t)(WhL + li * 512), 16, 0, 0);
    }

    float bv[4];
    #pragma unroll
    for (int g = 0; g < 4; ++g) bv[g] = bias[g * HSZ + hc0 + lr];

    // ---- x-projection (K quarter, direct global reads, no barriers) ----
    auto x_part = [&](const unsigned short* xt, f32x4 (&acc)[2][4]) {
        #pragma unroll
        for (int m = 0; m < 2; ++m)
            #pragma unroll
            for (int g = 0; g < 4; ++g)
                acc[m][g] = (kh == 0) ? (f32x4){bv[g], bv[g], bv[g], bv[g]}
                                      : (f32x4){0.f, 0.f, 0.f, 0.f};
        const unsigned short* xr = xt + (size_t)(b0 + q * 32 + lr) * ISZ + kh * 128 + kq * 8;
        const unsigned short* wr = Wihb + (size_t)(hc0 + lr) * ISZ + kh * 128 + kq * 8;
        bf16x8 a0 = *(const bf16x8*)xr;
        bf16x8 a1 = *(const bf16x8*)(xr + 16 * ISZ);
        #pragma unroll
        for (int j = 0; j < 4; ++j) {
            bf16x8 a0n = a0, a1n = a1;
            if (j < 3) {
                a0n = *(const bf16x8*)(xr + (j + 1) * 32);
                a1n = *(const bf16x8*)(xr + 16 * ISZ + (j + 1) * 32);
            }
            #pragma unroll
            for (int g = 0; g < 4; ++g) {
                bf16x8 wf = *(const bf16x8*)(wr + (size_t)g * HSZ * ISZ + j * 32);
                acc[0][g] = __builtin_amdgcn_mfma_f32_16x16x32_bf16(a0, wf, acc[0][g], 0, 0, 0);
                acc[1][g] = __builtin_amdgcn_mfma_f32_16x16x32_bf16(a1, wf, acc[1][g], 0, 0, 0);
            }
            a0 = a0n; a1 = a1n;
        }
    };

    // ---- recurrent GEMM (K quarter): acc += h_{t-1}[:, kh*256:+256] @ Whh^T ----
    auto h_gemm = [&](const unsigned short* hp, f32x4 (&acc)[2][4]) {
        const unsigned short* hr = hp + (size_t)(b0 + q * 32 + lr) * HSZ + kh * 256 + kq * 8;
        const char* WB = (const char*)WhL;
        bf16x8 a0 = *(const bf16x8*)hr;
        bf16x8 a1 = *(const bf16x8*)(hr + 16 * HSZ);
        #pragma unroll
        for (int c = 0; c < 8; ++c) {
            bf16x8 a0n = a0, a1n = a1;
            if (c < 7) {
                a0n = *(const bf16x8*)(hr + (c + 1) * 32);
                a1n = *(const bf16x8*)(hr + 16 * HSZ + (c + 1) * 32);
            }
            const int s = kh * 32 + c * 4 + kq;
            const int off = (s ^ (lr & 7)) << 4;
            #pragma unroll
            for (int g = 0; g < 4; ++g) {
                bf16x8 wf = *(const bf16x8*)(WB + (g * 16 + lr) * 2048 + off);
                acc[0][g] = __builtin_amdgcn_mfma_f32_16x16x32_bf16(a0, wf, acc[0][g], 0, 0, 0);
                acc[1][g] = __builtin_amdgcn_mfma_f32_16x16x32_bf16(a1, wf, acc[1][g], 0, 0, 0);
            }
            a0 = a0n; a1 = a1n;
        }
    };

    // ---- merge K quarters into kh==0 waves (bank-optimal 16KB rounds) ----
    auto kreduce = [&](f32x4 (&acc)[2][4]) {
        #pragma unroll
        for (int l = 1; l < 4; ++l) {
            #pragma unroll
            for (int m = 0; m < 2; ++m) {
                if (kh == l) {
                    #pragma unroll
                    for (int g = 0; g < 4; ++g)
                        *(f32x4*)&WS[q * 1024 + g * 256 + lane * 4] = acc[m][g];
                }
                __syncthreads();
                if (kh == 0) {
                    #pragma unroll
                    for (int g = 0; g < 4; ++g)
                        acc[m][g] += *(const f32x4*)&WS[q * 1024 + g * 256 + lane * 4];
                }
                __syncthreads();
            }
        }
    };

    f32x4 acc[2][4];
    f32x4 creg[2];
    creg[0] = (f32x4){0.f, 0.f, 0.f, 0.f};
    creg[1] = (f32x4){0.f, 0.f, 0.f, 0.f};

    x_part(xb, acc);                                   // acc for t=0 (overlaps W stage)
    asm volatile("s_waitcnt vmcnt(0)" ::: "memory");   // W_hh staged
    __syncthreads();

    float* hn = out + (size_t)TT * BSZ * HSZ;
    float* cn = hn + (size_t)BSZ * HSZ;
    const int n = hc0 + lr;

    for (int t = 0; t < TT; ++t) {
        if (t > 0) h_gemm((t & 1) ? hb0 : hb1, acc);
        kreduce(acc);

        // ---- LSTM pointwise (kh==0 waves own full gates); h->bf16 first ----
        f32x4 hv[2];
        if (kh == 0) {
            unsigned short* hbn = (t & 1) ? hb1 : hb0;
            #pragma unroll
            for (int m = 0; m < 2; ++m) {
                #pragma unroll
                for (int r = 0; r < 4; ++r) {
                    float gi = acc[m][0][r];
                    float gf = acc[m][1][r];
                    float gg = acc[m][2][r];
                    float go = acc[m][3][r];
                    float ig = 1.f / (1.f + __expf(-gi));
                    float fg = 1.f / (1.f + __expf(-gf));
                    float gv = 1.f - 2.f / (__expf(2.f * gg) + 1.f);
                    float og = 1.f / (1.f + __expf(-go));
                    float cnew = fg * creg[m][r] + ig * gv;
                    float h = og * (1.f - 2.f / (__expf(2.f * cnew) + 1.f));
                    creg[m][r] = cnew;
                    hv[m][r] = h;
                    const int b = b0 + q * 32 + m * 16 + kq * 4 + r;
                    hbn[(size_t)b * HSZ + n] = f2bf(h);
                }
            }
        }
        __syncthreads();   // all hbn stores drained (per-wave vmcnt0 at barrier)

        int* ctr = arrive + (size_t)t * 128 + mi * 32;
        if (t + 1 < TT) {
            if (tid == 0) {
                __threadfence();   // release: push hbn to device scope
                __hip_atomic_fetch_add(ctr, 1, __ATOMIC_RELAXED, __HIP_MEMORY_SCOPE_AGENT);
            }
            // deferred fp32 output stores (off the handshake critical path)
            if (kh == 0) {
                float* outt = out + (size_t)t * BSZ * HSZ;
                #pragma unroll
                for (int m = 0; m < 2; ++m)
                    #pragma unroll
                    for (int r = 0; r < 4; ++r) {
                        const int b = b0 + q * 32 + m * 16 + kq * 4 + r;
                        outt[(size_t)b * HSZ + n] = hv[m][r];
                    }
            }
            x_part(xb + (size_t)(t + 1) * BSZ * ISZ, acc);   // spin filler
            if (tid == 0) {
                while (__hip_atomic_load(ctr, __ATOMIC_RELAXED, __HIP_MEMORY_SCOPE_AGENT) < 64)
                    __builtin_amdgcn_s_sleep(2);
                __threadfence();   // acquire: invalidate L1/L2 before h reads
            }
            __syncthreads();
        } else {
            if (kh == 0) {
                float* outt = out + (size_t)t * BSZ * HSZ;
                #pragma unroll
                for (int m = 0; m < 2; ++m)
                    #pragma unroll
                    for (int r = 0; r < 4; ++r) {
                        const int b = b0 + q * 32 + m * 16 + kq * 4 + r;
                        const size_t idx = (size_t)b * HSZ + n;
                        outt[idx] = hv[m][r];
                        hn[idx] = hv[m][r];
                        cn[idx] = creg[m][r];
                    }
            }
        }
    }
}

extern "C" void kernel_launch(void* const* d_in, const int* in_sizes, int n_in,
                              void* d_out, int out_size, void* d_ws, size_t ws_size,
                              hipStream_t stream) {
    const float* input_ = (const float*)d_in[0];
    const float* Wih = (const float*)d_in[3];
    const float* Whh = (const float*)d_in[4];
    const float* bih = (const float*)d_in[5];
    const float* bhh = (const float*)d_in[6];

    char* ws = (char*)d_ws;
    unsigned short* Wihb = (unsigned short*)(ws);                 //  4 MB
    unsigned short* Whhb = (unsigned short*)(ws + (4u << 20));    //  8 MB
    unsigned short* xb   = (unsigned short*)(ws + (12u << 20));   // 32 MB
    float*          bias = (float*)(ws + (46u << 20));            // 16 KB
    int*            arr  = (int*)(ws + (47u << 20));              // 32 KB
    unsigned short* hbuf0 = (unsigned short*)(ws + (48u << 20));  //  1 MB
    unsigned short* hbuf1 = (unsigned short*)(ws + (49u << 20));  //  1 MB

    zero_arr<<<32, 256, 0, stream>>>(arr, 64 * 128);
    cast_f32_to_bf16<<<1024, 256, 0, stream>>>(Wih, Wihb, (4 * HSZ * ISZ) / 8);
    cast_f32_to_bf16<<<2048, 256, 0, stream>>>(Whh, Whhb, (4 * HSZ * HSZ) / 8);
    cast_f32_to_bf16<<<8192, 256, 0, stream>>>(input_, xb, (TT * BSZ * ISZ) / 8);
    bias_combine<<<16, 256, 0, stream>>>(bih, bhh, bias);

    float* out = (float*)d_out;
    lstm_persist<<<256, 1024, 0, stream>>>(xb, Wihb, Whhb, bias, out,
                                           hbuf0, hbuf1, arr);
}

// Round 8
// 1403.248 us; speedup vs baseline: 2.0649x; 2.0649x over previous
//
#include <hip/hip_runtime.h>

#define TT  64
#define BSZ 512
#define ISZ 512
#define HSZ 1024

typedef short bf16x8 __attribute__((ext_vector_type(8)));
typedef float f32x4 __attribute__((ext_vector_type(4)));
typedef unsigned short u16x8 __attribute__((ext_vector_type(8)));

typedef const __attribute__((address_space(1))) unsigned int* gas_t;
typedef __attribute__((address_space(3))) unsigned int* las_t;

__device__ __forceinline__ unsigned short f2bf(float f) {
    unsigned int u = __float_as_uint(f);
    unsigned int r = u + 0x7FFFu + ((u >> 16) & 1u);   // RNE
    return (unsigned short)(r >> 16);
}

__global__ void cast_f32_to_bf16(const float* __restrict__ in,
                                 unsigned short* __restrict__ out, int n8) {
    int i = blockIdx.x * blockDim.x + threadIdx.x;
    if (i >= n8) return;
    const float4* p = (const float4*)(in + (size_t)i * 8);
    float4 v0 = p[0], v1 = p[1];
    u16x8 o;
    o[0] = f2bf(v0.x); o[1] = f2bf(v0.y); o[2] = f2bf(v0.z); o[3] = f2bf(v0.w);
    o[4] = f2bf(v1.x); o[5] = f2bf(v1.y); o[6] = f2bf(v1.z); o[7] = f2bf(v1.w);
    *(u16x8*)(out + (size_t)i * 8) = o;
}

__global__ void bias_combine(const float* __restrict__ a,
                             const float* __restrict__ b,
                             float* __restrict__ o) {
    int i = blockIdx.x * blockDim.x + threadIdx.x;
    if (i < 4 * HSZ) o[i] = a[i] + b[i];
}

__global__ void zero_arr(int* p, int n) {
    int i = blockIdx.x * blockDim.x + threadIdx.x;
    if (i < n) p[i] = 0;
}

// Persistent LSTM. 256 blocks (1/CU via 144KB LDS), 512 threads = 8 waves
// (2/SIMD). Waves: mg = wv&3 (32 b-rows), ks = wv>>2 (K half of 512).
// Block (mi=bid>>6, ni=bid&63): b-rows [mi*128,+128), h-cols [ni*16,+16).
// W_hh slice LDS-resident (128KB, m201-pattern XOR swizzle).
// h ping-rotates through 64 per-step buffers, layout [64 ni][512 b][16c]
// (line-exclusive per producer block) -> NO acquire fences ever; consumer
// L2 lines are always first-touch-fresh; same-XCD blocks dedup via L2.
// Producer: __syncthreads + release-scope atomicAdd (wbl2, no invalidate).
__global__ __launch_bounds__(512, 2) void lstm_persist(
    const unsigned short* __restrict__ xb,    // [TT, BSZ, ISZ] bf16
    const unsigned short* __restrict__ Wihb,  // [4096, 512]
    const unsigned short* __restrict__ Whhb,  // [4096, 1024]
    const float* __restrict__ bias,           // [4096]
    float* __restrict__ out,                  // fp32 output
    unsigned short* __restrict__ hbs,         // [TT][64][512][16] bf16 rotation
    int* __restrict__ arrive)
{
    __shared__ unsigned short WhL[64 * 1024];   // 128 KiB persistent W_hh
    __shared__ float WS[4096];                  //  16 KiB k-reduce

    const int tid  = threadIdx.x;
    const int lane = tid & 63;
    const int wv   = tid >> 6;       // 0..7
    const int mg   = wv & 3;         // 32-row group
    const int ks   = wv >> 2;        // K half (0,1)
    const int lr   = lane & 15;
    const int kq   = lane >> 4;      // 0..3
    const int mi   = blockIdx.x >> 6;
    const int ni   = blockIdx.x & 63;
    const int b0   = mi * 128;
    const int hc0  = ni * 16;

    // ---- stage persistent W_hh slice (async; overlaps x_part(0)) ----
    // LDS[r][slot u] = G[r][u ^ (r&7)]  (16B slots; read undoes the XOR)
    #pragma unroll
    for (int i = 0; i < 16; ++i) {
        const int li = wv * 16 + i;            // 1KB unit, 0..127
        const int r = li >> 1, half = li & 1;
        const int grow = (r >> 4) * HSZ + hc0 + (r & 15);
        const int gslot = (half * 64 + lane) ^ (r & 7);
        const unsigned short* g = Whhb + (size_t)grow * HSZ + (size_t)gslot * 8;
        __builtin_amdgcn_global_load_lds((gas_t)g, (las_t)(WhL + li * 512), 16, 0, 0);
    }

    float bv[4];
    #pragma unroll
    for (int g = 0; g < 4; ++g) bv[g] = bias[g * HSZ + hc0 + lr];

    // ---- x-projection (K half, direct global, LDS-free) ----
    auto x_part = [&](const unsigned short* xt, f32x4 (&acc)[2][4]) {
        #pragma unroll
        for (int m = 0; m < 2; ++m)
            #pragma unroll
            for (int g = 0; g < 4; ++g)
                acc[m][g] = (ks == 0) ? (f32x4){bv[g], bv[g], bv[g], bv[g]}
                                      : (f32x4){0.f, 0.f, 0.f, 0.f};
        const unsigned short* xr = xt + (size_t)(b0 + mg * 32 + lr) * ISZ + ks * 256 + kq * 8;
        const unsigned short* wr = Wihb + (size_t)(hc0 + lr) * ISZ + ks * 256 + kq * 8;
        bf16x8 ax[2][8];
        #pragma unroll
        for (int c = 0; c < 8; ++c) {
            ax[0][c] = *(const bf16x8*)(xr + c * 32);
            ax[1][c] = *(const bf16x8*)(xr + 16 * ISZ + c * 32);
        }
        #pragma unroll
        for (int c = 0; c < 8; ++c) {
            #pragma unroll
            for (int g = 0; g < 4; ++g) {
                bf16x8 wf = *(const bf16x8*)(wr + (size_t)g * HSZ * ISZ + c * 32);
                acc[0][g] = __builtin_amdgcn_mfma_f32_16x16x32_bf16(ax[0][c], wf, acc[0][g], 0, 0, 0);
                acc[1][g] = __builtin_amdgcn_mfma_f32_16x16x32_bf16(ax[1][c], wf, acc[1][g], 0, 0, 0);
            }
        }
    };

    // ---- recurrent half-GEMM: acc += h_{t-1}[:, ks*512:+512] @ Whh^T ----
    // A from rotating h buffer (layout [ni'][b][16]); W from LDS.
    auto h_gemm = [&](const unsigned short* hp, f32x4 (&acc)[2][4]) {
        const int br0 = b0 + mg * 32 + lr;
        #pragma unroll
        for (int half = 0; half < 2; ++half) {
            bf16x8 a[2][8];
            #pragma unroll
            for (int c8 = 0; c8 < 8; ++c8) {
                const int c = half * 8 + c8;
                const int kc = ks * 512 + c * 32 + kq * 8;
                const size_t base = (size_t)(kc >> 4) * 8192 + (kc & 15);
                a[0][c8] = *(const bf16x8*)(hp + base + (size_t)br0 * 16);
                a[1][c8] = *(const bf16x8*)(hp + base + (size_t)(br0 + 16) * 16);
            }
            #pragma unroll
            for (int c8 = 0; c8 < 8; ++c8) {
                const int c = half * 8 + c8;
                const int u0 = ks * 64 + c * 4 + kq;
                const int off = ((u0 ^ (lr & 7)) << 4);
                #pragma unroll
                for (int g = 0; g < 4; ++g) {
                    bf16x8 wf = *(const bf16x8*)((const char*)WhL + (g * 16 + lr) * 2048 + off);
                    acc[0][g] = __builtin_amdgcn_mfma_f32_16x16x32_bf16(a[0][c8], wf, acc[0][g], 0, 0, 0);
                    acc[1][g] = __builtin_amdgcn_mfma_f32_16x16x32_bf16(a[1][c8], wf, acc[1][g], 0, 0, 0);
                }
            }
        }
    };

    f32x4 acc[2][4];
    f32x4 creg[2];
    creg[0] = (f32x4){0.f, 0.f, 0.f, 0.f};
    creg[1] = (f32x4){0.f, 0.f, 0.f, 0.f};

    x_part(xb, acc);                                   // acc for t=0
    asm volatile("s_waitcnt vmcnt(0)" ::: "memory");   // W_hh staged
    __syncthreads();

    float* hn = out + (size_t)TT * BSZ * HSZ;
    float* cn = hn + (size_t)BSZ * HSZ;
    const int n = hc0 + lr;

    for (int t = 0; t < TT; ++t) {
        if (t > 0) h_gemm(hbs + (size_t)(t - 1) * 524288, acc);

        // ---- merge K halves: ks=1 -> ks=0 (2 m-rounds, 16KB, lane-contig) ----
        #pragma unroll
        for (int m = 0; m < 2; ++m) {
            if (ks == 1) {
                #pragma unroll
                for (int g = 0; g < 4; ++g)
                    *(f32x4*)&WS[mg * 1024 + g * 256 + lane * 4] = acc[m][g];
            }
            __syncthreads();
            if (ks == 0) {
                #pragma unroll
                for (int g = 0; g < 4; ++g)
                    acc[m][g] += *(const f32x4*)&WS[mg * 1024 + g * 256 + lane * 4];
            }
            __syncthreads();
        }

        // ---- LSTM pointwise epilogue (ks==0 waves own full gates) ----
        if (ks == 0) {
            unsigned short* hslab = hbs + (size_t)t * 524288 + (size_t)ni * 8192;
            float* outt = out + (size_t)t * BSZ * HSZ;
            #pragma unroll
            for (int m = 0; m < 2; ++m) {
                #pragma unroll
                for (int r = 0; r < 4; ++r) {
                    const int b = b0 + mg * 32 + m * 16 + kq * 4 + r;
                    float gi = acc[m][0][r];
                    float gf = acc[m][1][r];
                    float gg = acc[m][2][r];
                    float go = acc[m][3][r];
                    float ig = 1.f / (1.f + __expf(-gi));
                    float fg = 1.f / (1.f + __expf(-gf));
                    float gv = 1.f - 2.f / (__expf(2.f * gg) + 1.f);
                    float og = 1.f / (1.f + __expf(-go));
                    float cnew = fg * creg[m][r] + ig * gv;
                    float h = og * (1.f - 2.f / (__expf(2.f * cnew) + 1.f));
                    creg[m][r] = cnew;
                    hslab[(size_t)b * 16 + lr] = f2bf(h);
                    outt[(size_t)b * HSZ + n] = h;
                    if (t == TT - 1) {
                        hn[(size_t)b * HSZ + n] = h;
                        cn[(size_t)b * HSZ + n] = creg[m][r];
                    }
                }
            }
        }

        if (t + 1 < TT) {
            __syncthreads();   // all h-slab stores drained to L2
            int* ctr = arrive + (size_t)t * 128 + mi * 32;
            if (tid == 0)      // release: wbl2 (writeback only), then arrive
                __hip_atomic_fetch_add(ctr, 1, __ATOMIC_RELEASE, __HIP_MEMORY_SCOPE_AGENT);
            x_part(xb + (size_t)(t + 1) * BSZ * ISZ, acc);   // spin filler
            if (tid == 0) {
                while (__hip_atomic_load(ctr, __ATOMIC_RELAXED, __HIP_MEMORY_SCOPE_AGENT) < 64)
                    __builtin_amdgcn_s_sleep(1);
            }
            __syncthreads();
        }
    }
}

extern "C" void kernel_launch(void* const* d_in, const int* in_sizes, int n_in,
                              void* d_out, int out_size, void* d_ws, size_t ws_size,
                              hipStream_t stream) {
    const float* input_ = (const float*)d_in[0];
    const float* Wih = (const float*)d_in[3];
    const float* Whh = (const float*)d_in[4];
    const float* bih = (const float*)d_in[5];
    const float* bhh = (const float*)d_in[6];

    char* ws = (char*)d_ws;
    unsigned short* Wihb = (unsigned short*)(ws);                 //  4 MB
    unsigned short* Whhb = (unsigned short*)(ws + (4u << 20));    //  8 MB
    unsigned short* xb   = (unsigned short*)(ws + (12u << 20));   // 32 MB
    float*          bias = (float*)(ws + (46u << 20));            // 16 KB
    int*            arr  = (int*)(ws + (47u << 20));              // 32 KB
    unsigned short* hbs  = (unsigned short*)(ws + (48u << 20));   // 64 MB rotation

    zero_arr<<<32, 256, 0, stream>>>(arr, 64 * 128);
    cast_f32_to_bf16<<<1024, 256, 0, stream>>>(Wih, Wihb, (4 * HSZ * ISZ) / 8);
    cast_f32_to_bf16<<<2048, 256, 0, stream>>>(Whh, Whhb, (4 * HSZ * HSZ) / 8);
    cast_f32_to_bf16<<<8192, 256, 0, stream>>>(input_, xb, (TT * BSZ * ISZ) / 8);
    bias_combine<<<16, 256, 0, stream>>>(bih, bhh, bias);

    float* out = (float*)d_out;
    lstm_persist<<<256, 512, 0, stream>>>(xb, Wihb, Whhb, bias, out, hbs, arr);
}